// Round 9
// baseline (577.283 us; speedup 1.0000x reference)
//
#include <hip/hip_runtime.h>

#define LL 50
#define TT 1024
#define BB 256
#define START_I 47
#define END_I 48
#define NW 8                     // blocks in fwd kernel, 32 chains each
#define NPREB 2048               // prepass blocks (256 thr = 4 waves each)
#define FOFF (TT * NW * 2048)    // floats in fbuf = 16,777,216 (64 MB)
#define RS 7                     // LDS ring slots (7 x 8KB = 56 KB)

typedef __attribute__((ext_vector_type(8))) short bh8;    // 8 bf16 (MFMA A/B frag)
typedef __attribute__((ext_vector_type(16))) float fx16;  // MFMA C/D frag
typedef __attribute__((ext_vector_type(4))) float fx4;
typedef __attribute__((ext_vector_type(4))) unsigned int ux4;

__device__ __forceinline__ unsigned int cvtpk_bf16(float lo, float hi) {
  unsigned int r;
  asm("v_cvt_pk_bf16_f32 %0, %1, %2" : "=v"(r) : "v"(lo), "v"(hi));
  return r;
}
// v_permlane32_swap_b32: A.hi-lanes <-> B.lo-lanes (VALU cross-half exchange)
__device__ __forceinline__ void pls(unsigned int& a, unsigned int& b) {
  asm("v_permlane32_swap_b32 %0, %1" : "+v"(a), "+v"(b));
}
// value of the paired lane (l ^ 32); full-exec contexts only
__device__ __forceinline__ float xpart(float x, bool hi) {
  unsigned int a = __float_as_uint(x), b = a;
  pls(a, b);
  return __uint_as_float(hi ? a : b);
}
__device__ __forceinline__ float rdlane(float v, int i) {
  return __int_as_float(__builtin_amdgcn_readlane(__float_as_int(v), i));
}
// un-sinkable 16B load; completion managed by manual counted s_waitcnt.
__device__ __forceinline__ void gload(fx4& d, const fx4* p) {
  asm volatile("global_load_dwordx4 %0, %1, off" : "=v"(d) : "v"(p));
}

// ============================================================================
// Pre-pass: identical to round-7/8 (bit-exact fbuf contents).
// ============================================================================
__global__ __launch_bounds__(256) void crf_prep(
    const float* __restrict__ lstm, const float* __restrict__ trans,
    const int* __restrict__ lens, const int* __restrict__ tags,
    float* __restrict__ fbuf, float* __restrict__ wsf) {
  if (blockIdx.x < NPREB) {
    const int wg = blockIdx.x * 4 + (threadIdx.x >> 6);  // 0..8191
    const int t = wg >> 3, w = wg & 7;
    const int lane = threadIdx.x & 63;
    const int h = lane >> 5, c31 = lane & 31;
    const int chain = w * 32 + c31;
    const float* row = lstm + ((size_t)chain * TT + t) * LL;
    fx4* dst = (fx4*)(fbuf + ((size_t)t * 8 + w) * 2048);
#pragma unroll
    for (int q = 0; q < 8; ++q) {
      fx4 v;
#pragma unroll
      for (int j = 0; j < 4; ++j) {
        int s = 32 * (q >> 2) + 8 * (q & 3) + 4 * h + j;
        v[j] = (s < LL) ? __expf(row[s]) : 0.f;
      }
      dst[q * 64 + lane] = v;
    }
  } else {
    const int b = blockIdx.x - NPREB;
    const int tid = threadIdx.x;
    const int* tg = tags + (size_t)b * TT;
    const int len = lens[b];
    float lab = 0.f;
    for (int t = 1 + tid; t < len; t += 256) {
      int tp = tg[t - 1], tc = tg[t];
      lab += trans[tp * LL + tc] + lstm[((size_t)b * TT + t) * LL + tc];
    }
#pragma unroll
    for (int off = 32; off > 0; off >>= 1) lab += __shfl_xor(lab, off, 64);
    if ((tid & 63) == 0) {
      int widx = tid >> 6;
      if (widx == 0) {
        int tg0 = tg[0], tgl = tg[len - 1];
        lab += trans[START_I * LL + tg0] + lstm[(size_t)b * TT * LL + tg0] +
               trans[tgl * LL + END_I];
      }
      wsf[BB + 4 * b + widx] = lab;
    }
  }
}

// ============================================================================
// Producer/consumer forward. 5 waves per block: waves 0-3 stream fbuf into a
// 7-slot LDS ring (each owns 2 of 8 fx4-vectors/step; 2-batch pipeline with
// counted vmcnt(8)); wave 4 runs the ROUND-8 BIT-EXACT recurrence reading fq
// from LDS (f32 bits pass through unchanged -> identical output bits).
// Flow control: volatile LDS counters. prodf[p]=steps produced by p; consf =
// steps consumed. Producer may write step s iff s - consf <= RS-1; consumer
// may read step s iff min(prodf) >= s+1. DS ops are per-wave in-order;
// lgkmcnt(0)+compiler barrier before each flag publish.
// ============================================================================
__global__ __launch_bounds__(320, 2) void crf_fwd_mfma(
    const float* __restrict__ trans, const int* __restrict__ lens,
    const float* __restrict__ fbuf, float* __restrict__ wsf) {
  __shared__ fx4 ring[RS][512];          // 56 KB
  __shared__ volatile unsigned prodf[4];
  __shared__ volatile unsigned consf;

  const int tid = threadIdx.x;
  const int wv = tid >> 6;
  const int lane = tid & 63;
  const int w = blockIdx.x;

  if (tid < 4) prodf[tid] = 0;
  if (tid == 4) consf = 0;
  __syncthreads();

  if (wv < 4) {
    // ------------------------------ producer ------------------------------
    const int p = wv;
    const fx4* __restrict__ fp = (const fx4*)fbuf;
    const fx4* bp = fp + (size_t)w * 512 + p * 128 + lane;  // i=2p at +0, 2p+1 at +64
    fx4 va[8], vb[8];
    unsigned cons_snap = 0;
    int slb = 0;  // slot of tb (incremental mod RS)

#define PISSUE(TB_, V_)                                          \
  {                                                              \
    _Pragma("unroll") for (int u_ = 0; u_ < 4; ++u_) {           \
      const fx4* q_ = bp + (size_t)((TB_) + u_) * (NW * 512);    \
      gload(V_[2 * u_], q_);                                     \
      gload(V_[2 * u_ + 1], q_ + 64);                            \
    }                                                            \
  }
#define PWRITE(TB_, V_)                                          \
  {                                                              \
    while ((int)cons_snap < (TB_)-3) {                           \
      __builtin_amdgcn_s_sleep(1);                               \
      cons_snap = consf;                                         \
    }                                                            \
    _Pragma("unroll") for (int u_ = 0; u_ < 4; ++u_) {           \
      int s_ = slb + u_;                                         \
      if (s_ >= RS) s_ -= RS;                                    \
      ring[s_][p * 128 + lane] = V_[2 * u_];                     \
      ring[s_][p * 128 + 64 + lane] = V_[2 * u_ + 1];            \
    }                                                            \
    asm volatile("s_waitcnt lgkmcnt(0)" ::: "memory");           \
    prodf[p] = (unsigned)((TB_) + 4);                            \
    slb += 4;                                                    \
    if (slb >= RS) slb -= RS;                                    \
  }

    PISSUE(0, va);
    for (int tb = 0; tb < TT; tb += 8) {
      // phase A: prefetch tb+4 -> vb, drain tb, publish tb (va)
      if (tb + 4 < TT) {
        PISSUE(tb + 4, vb);
        asm volatile("s_waitcnt vmcnt(8)" ::: "memory");
      } else {
        asm volatile("s_waitcnt vmcnt(0)" ::: "memory");
      }
      __builtin_amdgcn_sched_barrier(0);
      PWRITE(tb, va);
      // phase B: prefetch tb+8 -> va, drain tb+4, publish tb+4 (vb)
      if (tb + 8 < TT) {
        PISSUE(tb + 8, va);
        asm volatile("s_waitcnt vmcnt(8)" ::: "memory");
      } else {
        asm volatile("s_waitcnt vmcnt(0)" ::: "memory");
      }
      __builtin_amdgcn_sched_barrier(0);
      PWRITE(tb + 4, vb);
    }
#undef PISSUE
#undef PWRITE
  } else {
    // ------------------------------ consumer ------------------------------
    const int h = lane >> 5;
    const int c31 = lane & 31;
    const int chain = w * 32 + c31;
    const int len = lens[chain];
    const bool hi = (h == 1);

    // ---- A fragments (bit-exact R8) ----
    bh8 afr[2][4];
#pragma unroll
    for (int T = 0; T < 2; ++T)
#pragma unroll
      for (int c = 0; c < 4; ++c) {
        float ev[8];
#pragma unroll
        for (int d = 0; d < 8; ++d) {
          int si = 16 * c + 8 * h + d, so = 32 * T + c31;
          ev[d] = (si < LL && so < LL) ? __expf(trans[si * LL + so]) : 0.f;
        }
        ux4 dw = {cvtpk_bf16(ev[0], ev[1]), cvtpk_bf16(ev[2], ev[3]),
                  cvtpk_bf16(ev[4], ev[5]), cvtpk_bf16(ev[6], ev[7])};
        afr[T][c] = __builtin_bit_cast(bh8, dw);
      }

    float es0[16], es1[16];
#pragma unroll
    for (int r = 0; r < 16; ++r) {
      int sa = (r & 3) + 8 * (r >> 2) + 4 * h;
      es0[r] = __expf(trans[START_I * LL + sa]);
      int s1 = 32 + sa;
      es1[r] = (s1 < LL) ? __expf(trans[START_I * LL + s1]) : 0.f;
    }

    fx4 fqA[8], fqB[8];
    int availv = 0;
    int cnt = 0, cc = 0;
    float Zc = 1.0f;
    float sp = 1.0f;
    bool pend = false;
    bh8 bq[4];
    fx16 z16 = {};

    auto POLL = [&]() {
      unsigned a0 = prodf[0], a1 = prodf[1], a2 = prodf[2], a3 = prodf[3];
      unsigned m0 = a0 < a1 ? a0 : a1;
      unsigned m1 = a2 < a3 ? a2 : a3;
      availv = (int)(m0 < m1 ? m0 : m1);
    };
    auto CHECKTO = [&](int need) {
      if (availv < need) {
        POLL();
        while (availv < need) {
          __builtin_amdgcn_s_sleep(1);
          POLL();
        }
      }
      asm volatile("" ::: "memory");  // order ring reads after flag check
    };
    auto READF = [&](int sl, fx4(&fq)[8]) {
#pragma unroll
      for (int i = 0; i < 8; ++i) fq[i] = ring[sl][i * 64 + lane];
    };

    // ---- TAIL: bit-exact R8 TAILX (pack -> capture -> detect) ----
    auto TAIL = [&](int t, float(&d0)[16], float(&d1)[16]) {
      unsigned int P0[8], P1[8];
#pragma unroll
      for (int p_ = 0; p_ < 8; ++p_) {
        P0[p_] = cvtpk_bf16(d0[2 * p_], d0[2 * p_ + 1]);
        P1[p_] = cvtpk_bf16(d1[2 * p_], d1[2 * p_ + 1]);
      }
      pls(P0[0], P0[2]);
      pls(P0[1], P0[3]);
      pls(P0[4], P0[6]);
      pls(P0[5], P0[7]);
      pls(P1[0], P1[2]);
      pls(P1[1], P1[3]);
      pls(P1[4], P1[6]);
      pls(P1[5], P1[7]);
      ux4 w0_ = {P0[0], P0[1], P0[2], P0[3]};
      ux4 w1_ = {P0[4], P0[5], P0[6], P0[7]};
      ux4 w2_ = {P1[0], P1[1], P1[2], P1[3]};
      ux4 w3_ = {P1[4], P1[5], P1[6], P1[7]};
      bq[0] = __builtin_bit_cast(bh8, w0_);
      bq[1] = __builtin_bit_cast(bh8, w1_);
      bq[2] = __builtin_bit_cast(bh8, w2_);
      bq[3] = __builtin_bit_cast(bh8, w3_);
      if (__any(len == t + 1)) {  // rare
        float z_ = 0.f;
#pragma unroll
        for (int r_ = 0; r_ < 16; ++r_) {
          int sa_ = (r_ & 3) + 8 * (r_ >> 2) + 4 * h;
          z_ = fmaf(d0[r_], __expf(trans[sa_ * LL + END_I]), z_);
        }
#pragma unroll
        for (int r_ = 0; r_ < 16; ++r_) {
          int s1_ = 32 + (r_ & 3) + 8 * (r_ >> 2) + 4 * h;
          float e1_ = (s1_ < LL) ? __expf(trans[s1_ * LL + END_I]) : 0.f;
          z_ = fmaf(d1[r_], e1_, z_);
        }
        z_ += xpart(z_, hi);
        if (len == t + 1) {
          Zc = z_;
          cc = cnt;
        }
      }
      pend = false;
      sp = 1.0f;
      if (t & 1) {
        float mm[8];
#pragma unroll
        for (int r_ = 0; r_ < 8; ++r_)
          mm[r_] = fmaxf(fmaxf(d0[r_], d0[r_ + 8]), fmaxf(d1[r_], d1[r_ + 8]));
        mm[0] = fmaxf(mm[0], mm[4]);
        mm[1] = fmaxf(mm[1], mm[5]);
        mm[2] = fmaxf(mm[2], mm[6]);
        mm[3] = fmaxf(mm[3], mm[7]);
        float m_ = fmaxf(fmaxf(mm[0], mm[2]), fmaxf(mm[1], mm[3]));
        m_ = fmaxf(m_, xpart(m_, hi));
        bool trig_ = (m_ >= 0x1p64f);
        if (__any(trig_)) {
          sp = trig_ ? 0x1p-64f : 1.0f;
          cnt += trig_ ? 1 : 0;
          pend = true;
        }
      }
    };

    auto STEP = [&](int t, fx4(&FQ)[8], int sl, bool doRead) {
      fx16 ac0, ac1;
      ac0 = __builtin_amdgcn_mfma_f32_32x32x16_bf16(afr[0][0], bq[0], z16, 0, 0, 0);
      ac1 = __builtin_amdgcn_mfma_f32_32x32x16_bf16(afr[1][0], bq[0], z16, 0, 0, 0);
      ac0 = __builtin_amdgcn_mfma_f32_32x32x16_bf16(afr[0][1], bq[1], ac0, 0, 0, 0);
      ac1 = __builtin_amdgcn_mfma_f32_32x32x16_bf16(afr[1][1], bq[1], ac1, 0, 0, 0);
      ac0 = __builtin_amdgcn_mfma_f32_32x32x16_bf16(afr[0][2], bq[2], ac0, 0, 0, 0);
      ac1 = __builtin_amdgcn_mfma_f32_32x32x16_bf16(afr[1][2], bq[2], ac1, 0, 0, 0);
      ac0 = __builtin_amdgcn_mfma_f32_32x32x16_bf16(afr[0][3], bq[3], ac0, 0, 0, 0);
      ac1 = __builtin_amdgcn_mfma_f32_32x32x16_bf16(afr[1][3], bq[3], ac1, 0, 0, 0);
      if (pend) {
#pragma unroll
        for (int i = 0; i < 8; ++i) {
          FQ[i][0] *= sp;
          FQ[i][1] *= sp;
          FQ[i][2] *= sp;
          FQ[i][3] *= sp;
        }
      }
      float d0[16], d1[16];
#pragma unroll
      for (int r = 0; r < 16; ++r) {
        d0[r] = ac0[r] * FQ[r >> 2][r & 3];
        d1[r] = ac1[r] * FQ[4 + (r >> 2)][r & 3];
      }
      if (doRead) {
        CHECKTO(t + 3);  // t+2 < TT here, so t+3 <= TT = max produced
        READF(sl, FQ);
      }
      TAIL(t, d0, d1);
      if (lane == 0) consf = (unsigned)t;  // slots <= t fully read
    };

    // ---- prologue: fq0, fq1, t=0 block, fq2 ----
    CHECKTO(3);
    READF(0, fqA);
    READF(1, fqB);
    {
      float d0[16], d1[16];
#pragma unroll
      for (int r = 0; r < 16; ++r) {
        d0[r] = es0[r] * fqA[r >> 2][r & 3];
        d1[r] = es1[r] * fqA[4 + (r >> 2)][r & 3];
      }
      READF(2, fqA);
      TAIL(0, d0, d1);
      if (lane == 0) consf = 0u;
    }

    // ---- steps 1..1023; odd -> fqB, even -> fqA; read t+2 into same buf ----
    int s1 = 3, s2 = 4;
    int t = 1;
    for (; t + 2 < TT; t += 2) {
      STEP(t, fqB, s1, true);
      STEP(t + 1, fqA, s2, (t + 3) < TT);
      s1 += 2;
      if (s1 >= RS) s1 -= RS;
      s2 += 2;
      if (s2 >= RS) s2 -= RS;
    }
    STEP(TT - 1, fqB, 0, false);

    if (lane < 32)
      wsf[chain] = (float)cc * 44.361419555836498f + __logf(Zc);
  }
}

// ============================================================================
// Legacy fallback (proven round-3 kernel), used when ws_size < staging need.
// ============================================================================
__global__ __launch_bounds__(64) __attribute__((amdgpu_waves_per_eu(1, 1)))
void crf_fwd_legacy(
    const float* __restrict__ lstm, const float* __restrict__ trans,
    const int* __restrict__ lens, const int* __restrict__ tags,
    float* __restrict__ ws) {
  const int b = blockIdx.x;
  const int lane = threadIdx.x;
  const bool act = lane < LL;
  const int cl = act ? lane : (LL - 1);
  const int len = lens[b];

  float e[LL];
#pragma unroll
  for (int i = 0; i < LL; ++i) {
    float ev = __expf(trans[i * LL + cl]);
    e[i] = act ? ev : 0.0f;
  }
  const float* __restrict__ base = lstm + (size_t)b * TT * LL + cl;
  float q = act ? __expf(trans[START_I * LL + lane] + base[0]) : 0.0f;
  int cnt = 0;
  float s_pend = 1.0f;

  auto STEP = [&](float em) {
    float f = __expf(em) * s_pend;
    float acc0 = 0.f, acc1 = 0.f, acc2 = 0.f, acc3 = 0.f;
#pragma unroll
    for (int i = 0; i < 48; i += 4) {
      acc0 = fmaf(rdlane(q, i + 0), e[i + 0], acc0);
      acc1 = fmaf(rdlane(q, i + 1), e[i + 1], acc1);
      acc2 = fmaf(rdlane(q, i + 2), e[i + 2], acc2);
      acc3 = fmaf(rdlane(q, i + 3), e[i + 3], acc3);
    }
    acc0 = fmaf(rdlane(q, 48), e[48], acc0);
    acc1 = fmaf(rdlane(q, 49), e[49], acc1);
    float qn = ((acc0 + acc1) + (acc2 + acc3)) * f;
    unsigned long long up = __ballot(qn >= 0x1p64f);
    unsigned long long dn = __ballot(qn >= 0x1p-64f);
    s_pend = up ? 0x1p-64f : (dn ? 1.0f : 0x1p64f);
    cnt += up ? 1 : (dn ? 0 : -1);
    q = qn;
  };

  float ebuf[8];
  const float* p = base + LL;
#pragma unroll
  for (int k = 0; k < 8; ++k) ebuf[k] = p[k * LL];
  const int nb = (len - 1) >> 3;
  const int rem = (len - 1) & 7;
  for (int blk = 0; blk < nb; ++blk) {
    const float* pf = p + 8 * LL;
    if (blk < 126) {
#pragma unroll
      for (int u = 0; u < 8; ++u) {
        STEP(ebuf[u]);
        ebuf[u] = pf[u * LL];
      }
    } else {
#pragma unroll
      for (int u = 0; u < 8; ++u) {
        STEP(ebuf[u]);
        int tn = 9 + 8 * blk + u;
        if (tn < TT) ebuf[u] = pf[u * LL];
      }
    }
    p = pf;
  }
  for (int u = 0; u < rem; ++u) STEP(ebuf[u]);
  q *= s_pend;

  float wv = 0.0f;
  if (act) wv = q * __expf(trans[lane * LL + END_I]);
#pragma unroll
  for (int off = 32; off > 0; off >>= 1) wv += __shfl_xor(wv, off, 64);
  float unl = (float)cnt * 44.361419555836498f + __logf(wv);

  const int* tg = tags + (size_t)b * TT;
  float lab = 0.0f;
  for (int t0 = 0; t0 < len; t0 += 64) {
    int t = t0 + lane;
    if (t >= 1 && t < len) {
      int tp = tg[t - 1];
      int tc = tg[t];
      lab += trans[tp * LL + tc] + lstm[((size_t)b * TT + t) * LL + tc];
    }
  }
#pragma unroll
  for (int off = 32; off > 0; off >>= 1) lab += __shfl_xor(lab, off, 64);

  if (lane == 0) {
    int tg0 = tg[0];
    float begin = trans[START_I * LL + tg0] + lstm[(size_t)b * TT * LL + tg0];
    int tgl = tg[len - 1];
    float endv = trans[tgl * LL + END_I];
    ws[b] = unl;
    ws[BB + 4 * b] = lab + begin + endv;
    ws[BB + 4 * b + 1] = 0.f;
    ws[BB + 4 * b + 2] = 0.f;
    ws[BB + 4 * b + 3] = 0.f;
  }
}

// Deterministic final reduce: base[0..255] -> out[0]; base[256..1279] -> out[1]
__global__ __launch_bounds__(256) void crf_reduce(const float* __restrict__ base,
                                                  float* __restrict__ out) {
  __shared__ float sm[8];
  int tid = threadIdx.x;
  float u = base[tid];
  fx4 lv = ((const fx4*)(base + BB))[tid];
  float l = (lv[0] + lv[1]) + (lv[2] + lv[3]);
#pragma unroll
  for (int off = 32; off > 0; off >>= 1) {
    u += __shfl_xor(u, off, 64);
    l += __shfl_xor(l, off, 64);
  }
  int wid = tid >> 6;
  if ((tid & 63) == 0) {
    sm[wid] = u;
    sm[4 + wid] = l;
  }
  __syncthreads();
  if (tid == 0) {
    out[0] = (sm[0] + sm[1]) + (sm[2] + sm[3]);
    out[1] = (sm[4] + sm[5]) + (sm[6] + sm[7]);
  }
}

extern "C" void kernel_launch(void* const* d_in, const int* in_sizes, int n_in,
                              void* d_out, int out_size, void* d_ws, size_t ws_size,
                              hipStream_t stream) {
  const float* lstm = (const float*)d_in[0];
  const float* trans = (const float*)d_in[1];
  const int* lens = (const int*)d_in[2];
  const int* tags = (const int*)d_in[3];
  float* out = (float*)d_out;

  size_t need = (size_t)FOFF * 4 + (size_t)(BB * 5) * 4;
  if (ws_size >= need) {
    float* fbuf = (float*)d_ws;
    float* wsf = fbuf + FOFF;
    crf_prep<<<dim3(NPREB + BB), dim3(256), 0, stream>>>(lstm, trans, lens, tags,
                                                         fbuf, wsf);
    crf_fwd_mfma<<<dim3(NW), dim3(320), 0, stream>>>(trans, lens, fbuf, wsf);
    crf_reduce<<<dim3(1), dim3(256), 0, stream>>>(wsf, out);
  } else {
    float* wsf = (float*)d_ws;
    crf_fwd_legacy<<<dim3(BB), dim3(64), 0, stream>>>(lstm, trans, lens, tags, wsf);
    crf_reduce<<<dim3(1), dim3(256), 0, stream>>>(wsf, out);
  }
}

// Round 10
// 256.556 us; speedup vs baseline: 2.2501x; 2.2501x over previous
//
#include <hip/hip_runtime.h>

#define BB 256
#define TT 1024
#define LL 50
#define START_I 47
#define END_I 48

typedef __attribute__((ext_vector_type(4))) float fx4;

// One wave per sequence. Forward recurrence in scaled-linear domain:
//   q[j] = exp(alpha[j] - 64*ln2*cnt),  q_new[j] = (sum_i q[i]*E[i][j]) * exp(emit[j])
// E[i][j] = exp(trans[i][j]) held in 50 VGPRs (column j in lane j).
//
// Broadcast of q is via LDS (1 ds_write_b32 + 13 uniform-address ds_read_b128,
// both conflict-free) instead of 50 v_readlane — removes ~300cy/step of
// SGPR-write->VALU-read hazards on the serial critical path.
//
// Loop runs a FIXED 1023 steps; per-chain state is CAPTURED at t == len-1
// (trajectory for t <= len-1 is unaffected by later steps -> bit-exact to the
// round-3 kernel, which passed with absmax 0). Rescale is lazy: ballot picks
// s_pend in {2^-64,1,2^64}; folded into the NEXT step's emit factor f.
__global__ __launch_bounds__(64) __attribute__((amdgpu_waves_per_eu(1, 1)))
void crf_fwd(
    const float* __restrict__ lstm, const float* __restrict__ trans,
    const int* __restrict__ lens, const int* __restrict__ tags,
    float* __restrict__ ws) {
  __shared__ float sq[64];
  const int b = blockIdx.x;
  const int lane = threadIdx.x;
  const bool act = lane < LL;
  const int cl = act ? lane : (LL - 1);  // clamped column (49 = PAD, finite)
  const int len = lens[b];

  // ---- load E column (lane j holds E[0..49][j]); 0 for dead lanes ----
  float e[LL];
#pragma unroll
  for (int i = 0; i < LL; ++i) {
    float ev = __expf(trans[i * LL + cl]);
    e[i] = act ? ev : 0.0f;
  }

  const float* __restrict__ base = lstm + (size_t)b * TT * LL + cl;

  // ---- alpha0 -> q (dead lanes: q = 0); publish to LDS ----
  float q = act ? __expf(trans[START_I * LL + lane] + base[0]) : 0.0f;
  int cnt = 0;          // alpha = 64*ln2*cnt + ln(q * s_pend)
  float s_pend = 1.0f;  // pending rescale, folded into next f
  // captured state at t == len-1 (init = t==0 state, covers len==1)
  float qc = q, spc = 1.0f;
  int cc = 0;
  sq[lane] = q;

  // ---- one recurrence step (R3 bit-exact arithmetic, LDS broadcast) ----
  auto STEP = [&](int t, float em) {
    const fx4* qp = (const fx4*)sq;
    fx4 Q[13];
#pragma unroll
    for (int k = 0; k < 13; ++k) Q[k] = qp[k];  // uniform-addr broadcast reads
    float f = __expf(em) * s_pend;
    float a0 = 0.f, a1 = 0.f, a2 = 0.f, a3 = 0.f;
#pragma unroll
    for (int k = 0; k < 12; ++k) {  // same pairing/order as round-3 kernel
      a0 = fmaf(Q[k][0], e[4 * k + 0], a0);
      a1 = fmaf(Q[k][1], e[4 * k + 1], a1);
      a2 = fmaf(Q[k][2], e[4 * k + 2], a2);
      a3 = fmaf(Q[k][3], e[4 * k + 3], a3);
    }
    a0 = fmaf(Q[12][0], e[48], a0);
    a1 = fmaf(Q[12][1], e[49], a1);
    float qn = ((a0 + a1) + (a2 + a3)) * f;
    sq[lane] = qn;  // publish for next step ASAP (tail runs during latency)
    unsigned long long up = __ballot(qn >= 0x1p64f);
    unsigned long long dn = __ballot(qn >= 0x1p-64f);
    float sp_new = up ? 0x1p-64f : (dn ? 1.0f : 0x1p64f);
    int cn = cnt + (up ? 1 : (dn ? 0 : -1));
    if (t == len - 1) {  // wave-uniform capture (reproduces R3 post-loop state)
      qc = qn;
      spc = sp_new;
      cc = cn;
    }
    s_pend = sp_new;
    cnt = cn;
    q = qn;
  };

  // ---- prefetch ring, 8 deep, constant-immediate-offset loads ----
  float ebuf[8];
  const float* p = base + LL;  // t = 1
#pragma unroll
  for (int k = 0; k < 8; ++k) ebuf[k] = p[k * LL];  // t=1..8

  // fixed 1023 steps: 127 blocks of 8 (t=1..1016) + 7 remainder (t=1017..1023)
  for (int blk = 0; blk < 127; ++blk) {
    const float* pf = p + 8 * LL;  // refill source: t = tb+8+u
    const int tb = 1 + blk * 8;
    if (blk < 126) {  // refill t <= 1016+8 = 1024? no: tb+u+8 <= 1016 -> safe
#pragma unroll
      for (int u = 0; u < 8; ++u) {
        STEP(tb + u, ebuf[u]);
        ebuf[u] = pf[u * LL];
      }
    } else {  // last block: refill t = 1017..1024 -> guard row 1024
#pragma unroll
      for (int u = 0; u < 8; ++u) {
        STEP(tb + u, ebuf[u]);
        int tn = tb + u + 8;
        if (tn < TT) ebuf[u] = pf[u * LL];
      }
    }
    p = pf;
  }
#pragma unroll
  for (int u = 0; u < 7; ++u) STEP(1017 + u, ebuf[u]);

  // ---- unlabeled_b = 64*ln2*cc + ln( sum_j qc*spc * exp(trans[j][END]) ) ----
  float w = 0.0f;
  if (act) w = qc * spc * __expf(trans[lane * LL + END_I]);
#pragma unroll
  for (int off = 32; off > 0; off >>= 1) w += __shfl_xor(w, off, 64);
  float unl = (float)cc * 44.361419555836498f + __logf(w);

  // ---- labeled path (gathers over t in lane-strides of 64) ----
  const int* tg = tags + (size_t)b * TT;
  float lab = 0.0f;
  for (int t0 = 0; t0 < len; t0 += 64) {
    int t = t0 + lane;
    if (t >= 1 && t < len) {
      int tp = tg[t - 1];
      int tc = tg[t];
      lab += trans[tp * LL + tc] + lstm[((size_t)b * TT + t) * LL + tc];
    }
  }
#pragma unroll
  for (int off = 32; off > 0; off >>= 1) lab += __shfl_xor(lab, off, 64);

  if (lane == 0) {
    int tg0 = tg[0];
    float begin = trans[START_I * LL + tg0] + lstm[(size_t)b * TT * LL + tg0];
    int tgl = tg[len - 1];
    float endv = trans[tgl * LL + END_I];
    ws[b] = unl;
    ws[BB + b] = lab + begin + endv;
  }
}

// Deterministic final reduce: ws[0..255] -> out[0], ws[256..511] -> out[1]
__global__ __launch_bounds__(256) void crf_reduce(const float* __restrict__ ws,
                                                  float* __restrict__ out) {
  __shared__ float sm[8];
  int tid = threadIdx.x;
  float u = ws[tid];
  float l = ws[BB + tid];
#pragma unroll
  for (int off = 32; off > 0; off >>= 1) {
    u += __shfl_xor(u, off, 64);
    l += __shfl_xor(l, off, 64);
  }
  int wid = tid >> 6;
  if ((tid & 63) == 0) {
    sm[wid] = u;
    sm[4 + wid] = l;
  }
  __syncthreads();
  if (tid == 0) {
    out[0] = (sm[0] + sm[1]) + (sm[2] + sm[3]);
    out[1] = (sm[4] + sm[5]) + (sm[6] + sm[7]);
  }
}

extern "C" void kernel_launch(void* const* d_in, const int* in_sizes, int n_in,
                              void* d_out, int out_size, void* d_ws, size_t ws_size,
                              hipStream_t stream) {
  const float* lstm = (const float*)d_in[0];
  const float* trans = (const float*)d_in[1];
  const int* lens = (const int*)d_in[2];
  const int* tags = (const int*)d_in[3];
  float* ws = (float*)d_ws;
  float* out = (float*)d_out;

  crf_fwd<<<dim3(BB), dim3(64), 0, stream>>>(lstm, trans, lens, tags, ws);
  crf_reduce<<<dim3(1), dim3(256), 0, stream>>>(ws, out);
}

// Round 11
// 171.881 us; speedup vs baseline: 3.3586x; 1.4926x over previous
//
#include <hip/hip_runtime.h>

#define LL 50
#define TT 1024
#define BB 256
#define START_I 47
#define END_I 48
#define NS 48        // live states (rows/cols 48,49 provably inert)
#define CT 64        // chunk length in steps
#define NCH 15       // chunks k=0..14 cover steps 1+64k .. 64+64k (<=960)
#define MSTRIDE 2304 // 48*48 floats per chunk matrix

typedef __attribute__((ext_vector_type(8))) short bh8;
typedef __attribute__((ext_vector_type(16))) float fx16;
typedef __attribute__((ext_vector_type(4))) unsigned int ux4;

__device__ __forceinline__ unsigned int cvtpk_bf16(float lo, float hi) {
  unsigned int r;
  asm("v_cvt_pk_bf16_f32 %0, %1, %2" : "=v"(r) : "v"(lo), "v"(hi));
  return r;
}
__device__ __forceinline__ void pls(unsigned int& a, unsigned int& b) {
  asm("v_permlane32_swap_b32 %0, %1" : "+v"(a), "+v"(b));
}
__device__ __forceinline__ float rdlane(float v, int i) {
  return __int_as_float(__builtin_amdgcn_readlane(__float_as_int(v), i));
}
#define MFMA __builtin_amdgcn_mfma_f32_32x32x16_bf16

// ============================================================================
// Pass 1: per (chain b, chunk k) evolve the 48x48 transfer operator
//   M_k = prod_{t=1+64k}^{64+64k} diag(exp(emit_t)) E^T   (bf16 MFMA, f32 acc)
// Layouts are the R6-verified ones. Exact power-of-2 rescaling, count in Mc.
// Output: Mb[b][k][in*48 + out] (f32, via LDS transpose), scale count Mc[b][k].
// ============================================================================
__global__ __launch_bounds__(64) __attribute__((amdgpu_waves_per_eu(2)))
void crf_pass1(const float* __restrict__ lstm, const float* __restrict__ trans,
               float* __restrict__ Mb, int* __restrict__ Mc) {
  const int bk = blockIdx.x;
  const int b = bk / NCH;
  const int k = bk - b * NCH;
  const int lane = threadIdx.x;
  const int h = lane >> 5;
  const int c31 = lane & 31;

  // ---- A fragments (R6-verified): afr[T][kc], k-idx = 16kc+8h+d, out = 32T+c31
  bh8 afr[2][3];
#pragma unroll
  for (int T = 0; T < 2; ++T)
#pragma unroll
    for (int c = 0; c < 3; ++c) {
      float ev[8];
#pragma unroll
      for (int d = 0; d < 8; ++d) {
        int si = 16 * c + 8 * h + d, so = 32 * T + c31;  // si <= 47
        ev[d] = (so < LL) ? __expf(trans[si * LL + so]) : 0.f;
      }
      ux4 dw = {cvtpk_bf16(ev[0], ev[1]), cvtpk_bf16(ev[2], ev[3]),
                cvtpk_bf16(ev[4], ev[5]), cvtpk_bf16(ev[6], ev[7])};
      afr[T][c] = __builtin_bit_cast(bh8, dw);
    }

  // ---- f row indices: D-rows owned by this lane (16 of m-tile0, 8 of m-tile1)
  int ro[24];
#pragma unroll
  for (int r = 0; r < 16; ++r) ro[r] = (r & 3) + 8 * (r >> 2) + 4 * h;
#pragma unroll
  for (int r = 0; r < 8; ++r) ro[16 + r] = 32 + (r & 3) + 8 * (r >> 2) + 4 * h;

  // ---- identity seeds for B fragments (both n-tiles) ----
  bh8 bq0[3], bq1[3];
#pragma unroll
  for (int kc = 0; kc < 3; ++kc) {
    ux4 w0v, w1v;
#pragma unroll
    for (int wd = 0; wd < 4; ++wd) {
      int lo = 16 * kc + 8 * h + 2 * wd, hi2 = lo + 1;
      int col0 = c31, col1 = 32 + c31;
      w0v[wd] = (lo == col0 ? 0x3F80u : 0u) | (hi2 == col0 ? 0x3F800000u : 0u);
      w1v[wd] = (lo == col1 ? 0x3F80u : 0u) | (hi2 == col1 ? 0x3F800000u : 0u);
    }
    bq0[kc] = __builtin_bit_cast(bh8, w0v);
    bq1[kc] = __builtin_bit_cast(bh8, w1v);
  }

  const float* __restrict__ fb = lstm + ((size_t)b * TT + (1 + k * CT)) * LL;
  float fvA[24], fvB[24];
#pragma unroll
  for (int i = 0; i < 24; ++i) fvA[i] = fb[ro[i]];

  int cnt = 0;  // scale count in units of 2^32
  float d00[16], d01[16], d10[8], d11[8];
  fx16 z16 = {};

  auto STEP = [&](const float (&fv)[24], float (&fn)[24], const float* nrow,
                  bool check) {
    fx16 a00, a01, a10, a11;
    a00 = MFMA(afr[0][0], bq0[0], z16, 0, 0, 0);
    a10 = MFMA(afr[1][0], bq0[0], z16, 0, 0, 0);
    a01 = MFMA(afr[0][0], bq1[0], z16, 0, 0, 0);
    a11 = MFMA(afr[1][0], bq1[0], z16, 0, 0, 0);
    a00 = MFMA(afr[0][1], bq0[1], a00, 0, 0, 0);
    a10 = MFMA(afr[1][1], bq0[1], a10, 0, 0, 0);
    a01 = MFMA(afr[0][1], bq1[1], a01, 0, 0, 0);
    a11 = MFMA(afr[1][1], bq1[1], a11, 0, 0, 0);
    a00 = MFMA(afr[0][2], bq0[2], a00, 0, 0, 0);
    a10 = MFMA(afr[1][2], bq0[2], a10, 0, 0, 0);
    a01 = MFMA(afr[0][2], bq1[2], a01, 0, 0, 0);
    a11 = MFMA(afr[1][2], bq1[2], a11, 0, 0, 0);
    // prefetch next step's emits while MFMAs are in flight
#pragma unroll
    for (int i = 0; i < 24; ++i) fn[i] = nrow[ro[i]];
    // multiply rows by f = exp(emit)
#pragma unroll
    for (int r = 0; r < 16; ++r) {
      float ff = __expf(fv[r]);
      d00[r] = a00[r] * ff;
      d01[r] = a01[r] * ff;
    }
#pragma unroll
    for (int r = 0; r < 8; ++r) {
      float ff = __expf(fv[16 + r]);
      d10[r] = a10[r] * ff;
      d11[r] = a11[r] * ff;
    }
    if (check) {  // exact power-of-2 rescale, whole-matrix (wave-uniform)
      float mx = d00[0];
#pragma unroll
      for (int r = 1; r < 16; ++r) mx = fmaxf(mx, d00[r]);
#pragma unroll
      for (int r = 0; r < 16; ++r) mx = fmaxf(mx, d01[r]);
#pragma unroll
      for (int r = 0; r < 8; ++r) mx = fmaxf(mx, fmaxf(d10[r], d11[r]));
#pragma unroll
      for (int off = 32; off; off >>= 1) mx = fmaxf(mx, __shfl_xor(mx, off, 64));
      if (mx >= 0x1p32f) {
#pragma unroll
        for (int r = 0; r < 16; ++r) {
          d00[r] *= 0x1p-64f;
          d01[r] *= 0x1p-64f;
        }
#pragma unroll
        for (int r = 0; r < 8; ++r) {
          d10[r] *= 0x1p-64f;
          d11[r] *= 0x1p-64f;
        }
        cnt += 2;
      } else if (mx < 0x1p-16f) {
#pragma unroll
        for (int r = 0; r < 16; ++r) {
          d00[r] *= 0x1p32f;
          d01[r] *= 0x1p32f;
        }
#pragma unroll
        for (int r = 0; r < 8; ++r) {
          d10[r] *= 0x1p32f;
          d11[r] *= 0x1p32f;
        }
        cnt -= 1;
      }
    }
    // pack D -> next B (R6-verified cvtpk+permlane), per n-tile
    auto PACK = [&](float (&p0)[16], float (&p1)[8], bh8 (&bqo)[3]) {
      unsigned P0[8], P1[4];
#pragma unroll
      for (int p_ = 0; p_ < 8; ++p_) P0[p_] = cvtpk_bf16(p0[2 * p_], p0[2 * p_ + 1]);
#pragma unroll
      for (int p_ = 0; p_ < 4; ++p_) P1[p_] = cvtpk_bf16(p1[2 * p_], p1[2 * p_ + 1]);
      pls(P0[0], P0[2]);
      pls(P0[1], P0[3]);
      pls(P0[4], P0[6]);
      pls(P0[5], P0[7]);
      pls(P1[0], P1[2]);
      pls(P1[1], P1[3]);
      ux4 w0 = {P0[0], P0[1], P0[2], P0[3]};
      ux4 w1 = {P0[4], P0[5], P0[6], P0[7]};
      ux4 w2 = {P1[0], P1[1], P1[2], P1[3]};
      bqo[0] = __builtin_bit_cast(bh8, w0);
      bqo[1] = __builtin_bit_cast(bh8, w1);
      bqo[2] = __builtin_bit_cast(bh8, w2);
    };
    PACK(d00, d10, bq0);
    PACK(d01, d11, bq1);
  };

  for (int uu = 0; uu < CT; uu += 2) {
    STEP(fvA, fvB, fb + (size_t)(uu + 1) * LL, false);
    STEP(fvB, fvA, fb + (size_t)(uu + 2) * LL, true);  // row <=961: in-bounds
  }

  // ---- epilogue: LDS transpose (lt[out][in]) -> coalesced store [in][out] ----
  __shared__ float lt[NS][NS + 1];
#pragma unroll
  for (int r = 0; r < 16; ++r) lt[ro[r]][c31] = d00[r];
#pragma unroll
  for (int r = 0; r < 8; ++r) lt[ro[16 + r]][c31] = d10[r];
  if (c31 < 16) {
#pragma unroll
    for (int r = 0; r < 16; ++r) lt[ro[r]][32 + c31] = d01[r];
#pragma unroll
    for (int r = 0; r < 8; ++r) lt[ro[16 + r]][32 + c31] = d11[r];
  }
  __syncthreads();
  float* __restrict__ mg = Mb + ((size_t)b * NCH + k) * MSTRIDE;
  if (lane < NS) {
#pragma unroll
    for (int s = 0; s < NS; ++s) mg[s * NS + lane] = lt[lane][s];
  }
  if (lane == 0) Mc[b * NCH + k] = cnt;
}

// ============================================================================
// Pass 2: per chain, apply K full-chunk matrices (f32 readlane matvec), then
// <=63 remainder steps with the R3-bit-equal f32 step, then Z + labeled path.
// ============================================================================
__global__ __launch_bounds__(64) __attribute__((amdgpu_waves_per_eu(1, 1)))
void crf_pass2(const float* __restrict__ lstm, const float* __restrict__ trans,
               const int* __restrict__ lens, const int* __restrict__ tags,
               const float* __restrict__ Mb, const int* __restrict__ Mc,
               float* __restrict__ wsf) {
  const int b = blockIdx.x;
  const int lane = threadIdx.x;
  const bool act = lane < NS;
  const int cl = act ? lane : (NS - 1);
  const int len = lens[b];
  const int L = len - 1;
  const int K = L >> 6;
  const int r = L & 63;

  // E columns f32 (48 live states; cols 48/49 provably inert)
  float e[NS];
#pragma unroll
  for (int i = 0; i < NS; ++i) {
    float ev = __expf(trans[i * LL + cl]);
    e[i] = act ? ev : 0.0f;
  }

  const float* __restrict__ base = lstm + (size_t)b * TT * LL;
  float alpha = act ? __expf(trans[START_I * LL + lane] + base[cl]) : 0.0f;
  int cnt32 = 0;  // units of 2^32

  // ---- chunk applies ----
  const float* __restrict__ mgb = Mb + (size_t)b * NCH * MSTRIDE;
  float mcur[NS], mnxt[NS];
  if (K > 0) {
#pragma unroll
    for (int i = 0; i < NS; ++i) mcur[i] = mgb[i * NS + cl];
  }
  for (int k = 0; k < K; ++k) {
    if (k + 1 < K) {
      const float* mgp = mgb + (size_t)(k + 1) * MSTRIDE;
#pragma unroll
      for (int i = 0; i < NS; ++i) mnxt[i] = mgp[i * NS + cl];
    }
    float a0 = 0.f, a1 = 0.f, a2 = 0.f, a3 = 0.f;
#pragma unroll
    for (int i = 0; i < NS; i += 4) {
      a0 = fmaf(rdlane(alpha, i + 0), mcur[i + 0], a0);
      a1 = fmaf(rdlane(alpha, i + 1), mcur[i + 1], a1);
      a2 = fmaf(rdlane(alpha, i + 2), mcur[i + 2], a2);
      a3 = fmaf(rdlane(alpha, i + 3), mcur[i + 3], a3);
    }
    float an = (a0 + a1) + (a2 + a3);
    unsigned long long up = __ballot(an >= 0x1p64f);
    unsigned long long dn = __ballot(an >= 0x1p-64f);
    float s = up ? 0x1p-64f : (dn ? 1.0f : 0x1p64f);
    cnt32 += up ? 2 : (dn ? 0 : -2);
    alpha = an * s;
    cnt32 += Mc[b * NCH + k];
    if (k + 1 < K) {
#pragma unroll
      for (int i = 0; i < NS; ++i) mcur[i] = mnxt[i];
    }
  }

  // ---- remainder steps t = 64K+1 .. 64K+r (R3-bit-equal f32 step) ----
  auto VSTEP = [&](float em) {
    float f = __expf(em);
    float a0 = 0.f, a1 = 0.f, a2 = 0.f, a3 = 0.f;
#pragma unroll
    for (int i = 0; i < NS; i += 4) {
      a0 = fmaf(rdlane(alpha, i + 0), e[i + 0], a0);
      a1 = fmaf(rdlane(alpha, i + 1), e[i + 1], a1);
      a2 = fmaf(rdlane(alpha, i + 2), e[i + 2], a2);
      a3 = fmaf(rdlane(alpha, i + 3), e[i + 3], a3);
    }
    float qn = ((a0 + a1) + (a2 + a3)) * f;
    unsigned long long up = __ballot(qn >= 0x1p64f);
    unsigned long long dn = __ballot(qn >= 0x1p-64f);
    float s = up ? 0x1p-64f : (dn ? 1.0f : 0x1p64f);
    cnt32 += up ? 2 : (dn ? 0 : -2);
    alpha = qn * s;
  };

  {
    const float* p = base + (size_t)(64 * K + 1) * LL + cl;  // rows <=968 valid
    float ebuf[8];
#pragma unroll
    for (int kk = 0; kk < 8; ++kk) ebuf[kk] = p[(size_t)kk * LL];
    int u = 0;
    for (; u + 8 <= r; u += 8) {
#pragma unroll
      for (int s8 = 0; s8 < 8; ++s8) {
        VSTEP(ebuf[s8]);
        int tn = u + s8 + 8;
        tn = (tn < r) ? tn : 0;  // clamp: unused slots read a valid row
        ebuf[s8] = p[(size_t)tn * LL];
      }
    }
    if (u + 0 < r) VSTEP(ebuf[0]);
    if (u + 1 < r) VSTEP(ebuf[1]);
    if (u + 2 < r) VSTEP(ebuf[2]);
    if (u + 3 < r) VSTEP(ebuf[3]);
    if (u + 4 < r) VSTEP(ebuf[4]);
    if (u + 5 < r) VSTEP(ebuf[5]);
    if (u + 6 < r) VSTEP(ebuf[6]);
  }

  // ---- unlabeled = 32*ln2*cnt32 + ln( sum_j alpha_j * exp(trans[j][END]) )
  float w = 0.0f;
  if (act) w = alpha * __expf(trans[lane * LL + END_I]);
#pragma unroll
  for (int off = 32; off > 0; off >>= 1) w += __shfl_xor(w, off, 64);
  float unl = (float)cnt32 * 22.180709777918249f + __logf(w);

  // ---- labeled path (R3 verbatim) ----
  const int* tg = tags + (size_t)b * TT;
  float lab = 0.0f;
  for (int t0 = 0; t0 < len; t0 += 64) {
    int t = t0 + lane;
    if (t >= 1 && t < len) {
      int tp = tg[t - 1];
      int tc = tg[t];
      lab += trans[tp * LL + tc] + lstm[((size_t)b * TT + t) * LL + tc];
    }
  }
#pragma unroll
  for (int off = 32; off > 0; off >>= 1) lab += __shfl_xor(lab, off, 64);

  if (lane == 0) {
    int tg0 = tg[0];
    float begin = trans[START_I * LL + tg0] + lstm[(size_t)b * TT * LL + tg0];
    int tgl = tg[len - 1];
    float endv = trans[tgl * LL + END_I];
    wsf[b] = unl;
    wsf[BB + b] = lab + begin + endv;
  }
}

// ============================================================================
// Legacy fallback: round-3 kernel (proven, absmax 0), if ws too small.
// ============================================================================
__global__ __launch_bounds__(64) __attribute__((amdgpu_waves_per_eu(1, 1)))
void crf_fwd_legacy(
    const float* __restrict__ lstm, const float* __restrict__ trans,
    const int* __restrict__ lens, const int* __restrict__ tags,
    float* __restrict__ ws) {
  const int b = blockIdx.x;
  const int lane = threadIdx.x;
  const bool act = lane < LL;
  const int cl = act ? lane : (LL - 1);
  const int len = lens[b];

  float e[LL];
#pragma unroll
  for (int i = 0; i < LL; ++i) {
    float ev = __expf(trans[i * LL + cl]);
    e[i] = act ? ev : 0.0f;
  }
  const float* __restrict__ base = lstm + (size_t)b * TT * LL + cl;
  float q = act ? __expf(trans[START_I * LL + lane] + base[0]) : 0.0f;
  int cnt = 0;
  float s_pend = 1.0f;

  auto STEP = [&](float em) {
    float f = __expf(em) * s_pend;
    float acc0 = 0.f, acc1 = 0.f, acc2 = 0.f, acc3 = 0.f;
#pragma unroll
    for (int i = 0; i < 48; i += 4) {
      acc0 = fmaf(rdlane(q, i + 0), e[i + 0], acc0);
      acc1 = fmaf(rdlane(q, i + 1), e[i + 1], acc1);
      acc2 = fmaf(rdlane(q, i + 2), e[i + 2], acc2);
      acc3 = fmaf(rdlane(q, i + 3), e[i + 3], acc3);
    }
    acc0 = fmaf(rdlane(q, 48), e[48], acc0);
    acc1 = fmaf(rdlane(q, 49), e[49], acc1);
    float qn = ((acc0 + acc1) + (acc2 + acc3)) * f;
    unsigned long long up = __ballot(qn >= 0x1p64f);
    unsigned long long dn = __ballot(qn >= 0x1p-64f);
    s_pend = up ? 0x1p-64f : (dn ? 1.0f : 0x1p64f);
    cnt += up ? 1 : (dn ? 0 : -1);
    q = qn;
  };

  float ebuf[8];
  const float* p = base + LL;
#pragma unroll
  for (int k = 0; k < 8; ++k) ebuf[k] = p[k * LL];
  const int nb = (len - 1) >> 3;
  const int rem = (len - 1) & 7;
  for (int blk = 0; blk < nb; ++blk) {
    const float* pf = p + 8 * LL;
    if (blk < 126) {
#pragma unroll
      for (int u = 0; u < 8; ++u) {
        STEP(ebuf[u]);
        ebuf[u] = pf[u * LL];
      }
    } else {
#pragma unroll
      for (int u = 0; u < 8; ++u) {
        STEP(ebuf[u]);
        int tn = 9 + 8 * blk + u;
        if (tn < TT) ebuf[u] = pf[u * LL];
      }
    }
    p = pf;
  }
  for (int u = 0; u < rem; ++u) STEP(ebuf[u]);
  q *= s_pend;

  float wv = 0.0f;
  if (act) wv = q * __expf(trans[lane * LL + END_I]);
#pragma unroll
  for (int off = 32; off > 0; off >>= 1) wv += __shfl_xor(wv, off, 64);
  float unl = (float)cnt * 44.361419555836498f + __logf(wv);

  const int* tg = tags + (size_t)b * TT;
  float lab = 0.0f;
  for (int t0 = 0; t0 < len; t0 += 64) {
    int t = t0 + lane;
    if (t >= 1 && t < len) {
      int tp = tg[t - 1];
      int tc = tg[t];
      lab += trans[tp * LL + tc] + lstm[((size_t)b * TT + t) * LL + tc];
    }
  }
#pragma unroll
  for (int off = 32; off > 0; off >>= 1) lab += __shfl_xor(lab, off, 64);

  if (lane == 0) {
    int tg0 = tg[0];
    float begin = trans[START_I * LL + tg0] + lstm[(size_t)b * TT * LL + tg0];
    int tgl = tg[len - 1];
    float endv = trans[tgl * LL + END_I];
    ws[b] = unl;
    ws[BB + b] = lab + begin + endv;
  }
}

// Deterministic final reduce: ws[0..255] -> out[0], ws[256..511] -> out[1]
__global__ __launch_bounds__(256) void crf_reduce(const float* __restrict__ ws,
                                                  float* __restrict__ out) {
  __shared__ float sm[8];
  int tid = threadIdx.x;
  float u = ws[tid];
  float l = ws[BB + tid];
#pragma unroll
  for (int off = 32; off > 0; off >>= 1) {
    u += __shfl_xor(u, off, 64);
    l += __shfl_xor(l, off, 64);
  }
  int wid = tid >> 6;
  if ((tid & 63) == 0) {
    sm[wid] = u;
    sm[4 + wid] = l;
  }
  __syncthreads();
  if (tid == 0) {
    out[0] = (sm[0] + sm[1]) + (sm[2] + sm[3]);
    out[1] = (sm[4] + sm[5]) + (sm[6] + sm[7]);
  }
}

extern "C" void kernel_launch(void* const* d_in, const int* in_sizes, int n_in,
                              void* d_out, int out_size, void* d_ws, size_t ws_size,
                              hipStream_t stream) {
  const float* lstm = (const float*)d_in[0];
  const float* trans = (const float*)d_in[1];
  const int* lens = (const int*)d_in[2];
  const int* tags = (const int*)d_in[3];
  float* out = (float*)d_out;

  size_t need = (size_t)BB * NCH * MSTRIDE * 4 + (size_t)BB * NCH * 4 +
                (size_t)BB * 2 * 4;
  if (ws_size >= need) {
    float* Mb = (float*)d_ws;
    int* Mc = (int*)(Mb + (size_t)BB * NCH * MSTRIDE);
    float* wsf = (float*)(Mc + BB * NCH);
    crf_pass1<<<dim3(BB * NCH), dim3(64), 0, stream>>>(lstm, trans, Mb, Mc);
    crf_pass2<<<dim3(BB), dim3(64), 0, stream>>>(lstm, trans, lens, tags, Mb, Mc,
                                                 wsf);
    crf_reduce<<<dim3(1), dim3(256), 0, stream>>>(wsf, out);
  } else {
    float* wsf = (float*)d_ws;
    crf_fwd_legacy<<<dim3(BB), dim3(64), 0, stream>>>(lstm, trans, lens, tags, wsf);
    crf_reduce<<<dim3(1), dim3(256), 0, stream>>>(wsf, out);
  }
}